// Round 7
// baseline (98.450 us; speedup 1.0000x reference)
//
#include <hip/hip_runtime.h>
#include <stdint.h>

#define BB   16
#define NGT  128
#define LL   8400
#define CC   80
#define KTOP 13
#define SEGW 2112      // 33 iterations * 64 lanes; 4 segments cover 8400
#define FEPS 1e-9f

typedef float vfloat4 __attribute__((ext_vector_type(4)));

__device__ __forceinline__ float iou_f(float4 g, float4 p) {
    float ix0 = fmaxf(g.x, p.x);
    float iy0 = fmaxf(g.y, p.y);
    float ix1 = fminf(g.z, p.z);
    float iy1 = fminf(g.w, p.w);
    float ow = fmaxf(ix1 - ix0, 0.0f);
    float oh = fmaxf(iy1 - iy0, 0.0f);
    float ov = ow * oh;
    float a1 = fmaxf(g.z - g.x, 0.0f) * fmaxf(g.w - g.y, 0.0f);
    float a2 = fmaxf(p.z - p.x, 0.0f) * fmaxf(p.w - p.y, 0.0f);
    return ov / (a1 + a2 - ov + FEPS);
}

// --------- Kernel A: exact top-13 per (b,gt) row + fused claim -------------
// One BLOCK (4 waves) per row; wave w scans contiguous segment
// [w*2112, min((w+1)*2112, 8400)) via register bitmask (33 iters, no LDS,
// no ballot). Phase 2 walks own bits: bbox gather (L2) + iou; score gather
// only if iou>0 (iou==0 -> metric exactly 0.0 in reference). Stage-1 merge
// per wave (13 rounds argmax+pop), stage-2 wave 0 over 4x13, 13-lane claims.
// Key = (metric_bits << 32) | ~j -> max-order == (value desc, index asc),
// exactly jax.lax.top_k tie semantics. Zero-fill slots covered by in-box
// zero-iou candidates + virtual zero key ~lane (wave 0) when j=lane outside.
__global__ __launch_bounds__(256) void topk_kernel(
    const float*  __restrict__ pred_scores,   // B,L,C
    const float4* __restrict__ pred_bboxes,   // B,L
    const float2* __restrict__ anchors,       // L
    const int*    __restrict__ gt_labels,     // B,n
    const float4* __restrict__ gt_bboxes,     // B,n
    int* __restrict__ claim_count,            // B,L (zeroed)
    int* __restrict__ claimant)               // B,L (zeroed)
{
    int wave = threadIdx.x >> 6;
    int lane = threadIdx.x & 63;
    int row  = blockIdx.x;                    // b*NGT + i
    int b    = row >> 7;
    int i_gt = row & (NGT - 1);

    float4 g  = gt_bboxes[row];
    int label = gt_labels[row];
    const float*  sc = pred_scores + (size_t)b * LL * CC + label;
    const float4* pb = pred_bboxes + (size_t)b * LL;

    __shared__ unsigned long long wkeys[4 * KTOP];
    __shared__ int s_pick[KTOP];

    // ---- Phase 1: pure-VALU in-box scan of own segment -> register mask ----
    int seg  = wave * SEGW;
    int jend = (seg + SEGW < LL) ? seg + SEGW : LL;
    unsigned long long m0 = 0ull;
#pragma unroll 4
    for (int it = 0; it < 33; ++it) {
        int j = seg + (it << 6) + lane;
        if (j < jend) {
            float2 ap = anchors[j];
            float d = fminf(fminf(ap.x - g.x, ap.y - g.y),
                            fminf(g.z - ap.x, g.w - ap.y));
            m0 |= ((unsigned long long)(d > FEPS)) << it;
        }
    }

    // ---- Phase 2: per-lane top-13 over own candidates ----
    unsigned long long keys[KTOP];
#pragma unroll
    for (int k = 0; k < KTOP; ++k) keys[k] = 0ull;

    // virtual zero-metric key for j = lane (< 64), wave 0, outside the box
    if (wave == 0 && !(m0 & 1ull)) keys[0] = (unsigned)(~(unsigned)lane);

    {
        unsigned long long mask = m0;
        while (mask) {
            int p = __ffsll(mask) - 1;
            mask &= mask - 1ull;
            int j = seg + (p << 6) + lane;
            float4 pbx = pb[j];                      // L2-resident gather
            float iou = iou_f(g, pbx);
            unsigned long long key = (unsigned)(~(unsigned)j);
            if (iou > 0.0f) {                        // ~10%: score gather
                float s  = sc[(size_t)j * CC];
                float i2 = iou * iou;
                key |= ((unsigned long long)__float_as_uint(s * (i2 * i2 * i2)) << 32);
            }
            if (key > keys[KTOP - 1]) {
                keys[KTOP - 1] = key;
#pragma unroll
                for (int k = KTOP - 1; k > 0; --k) {
                    unsigned long long a = keys[k - 1], c2 = keys[k];
                    keys[k - 1] = (c2 > a) ? c2 : a;
                    keys[k]     = (c2 > a) ? a : c2;
                }
            }
        }
    }

    // ---- Stage 1: per-wave top-13 (13 rounds wave-argmax + owner-pop) ----
    for (int r = 0; r < KTOP; ++r) {
        unsigned long long head = keys[0];
        unsigned long long m = head;
#pragma unroll
        for (int off = 1; off < 64; off <<= 1) {
            unsigned long long o = __shfl_xor(m, off, 64);
            if (o > m) m = o;
        }
        if (head == m && m != 0ull) {   // unique owner (keys distinct)
#pragma unroll
            for (int k = 0; k < KTOP - 1; ++k) keys[k] = keys[k + 1];
            keys[KTOP - 1] = 0ull;
        }
        if (lane == 0) wkeys[wave * KTOP + r] = m;
    }
    __syncthreads();

    // ---- Stage 2: wave 0 merges the 4 sorted 13-lists (52 keys) ----
    if (wave == 0) {
        unsigned long long k1 = (lane < 4 * KTOP) ? wkeys[lane] : 0ull;
        for (int r = 0; r < KTOP; ++r) {
            unsigned long long m = k1;
#pragma unroll
            for (int off = 1; off < 64; off <<= 1) {
                unsigned long long o = __shfl_xor(m, off, 64);
                if (o > m) m = o;
            }
            if (k1 == m && m != 0ull) k1 = 0ull;   // pop
            if (lane == 0) s_pick[r] = (int)(~(unsigned)(m & 0xFFFFFFFFull));
        }
    }
    __syncthreads();

    // ---- Fused claim: recheck in-box per pick, parallel scatter atomics ----
    if (threadIdx.x < KTOP) {
        int j = s_pick[threadIdx.x];
        float2 ap = anchors[j];
        float d = fminf(fminf(ap.x - g.x, ap.y - g.y),
                        fminf(g.z - ap.x, g.w - ap.y));
        if (d > FEPS) {
            atomicAdd(claim_count + b * LL + j, 1);
            atomicMax(claimant + b * LL + j, i_gt);
        }
    }
}

// ------- Kernel C: resolve contested + per-GT maxes + labels/bboxes --------
__global__ __launch_bounds__(256) void resolve_kernel(
    const float*  __restrict__ pred_scores,
    const float4* __restrict__ pred_bboxes,
    const int*    __restrict__ gt_labels,
    const float4* __restrict__ gt_bboxes,
    const int*    __restrict__ claim_count,
    const int*    __restrict__ claimant,
    int*      __restrict__ assigned_gt,
    float*    __restrict__ align_anchor,
    unsigned* __restrict__ max_metric,
    unsigned* __restrict__ max_iou,
    float*    __restrict__ out_labels,
    float4*   __restrict__ out_bboxes)
{
    int b = blockIdx.y;
    int j = blockIdx.x * 256 + threadIdx.x;

    __shared__ float4 gbox[NGT];
    __shared__ int    glab[NGT];
    if (threadIdx.x < NGT) {
        gbox[threadIdx.x] = gt_bboxes[b * NGT + threadIdx.x];
        glab[threadIdx.x] = gt_labels[b * NGT + threadIdx.x];
    }
    __syncthreads();
    if (j >= LL) return;

    int idx = b * LL + j;
    int cnt = claim_count[idx];
    int g = -1;
    float4 p = pred_bboxes[(size_t)b * LL + j];

    if (cnt == 1) {
        g = claimant[idx];
    } else if (cnt > 1) {
        // argmax_i iou over ALL gts, first-max tie-break (strict >)
        float best = -1.0f;
        int   bi   = 0;
        for (int i = 0; i < NGT; ++i) {
            float iou = iou_f(gbox[i], p);
            if (iou > best) { best = iou; bi = i; }
        }
        g = bi;
    }
    assigned_gt[idx] = g;

    int label; float4 bb;
    if (g >= 0) {
        float iou = iou_f(gbox[g], p);
        float s   = pred_scores[((size_t)b * LL + j) * CC + glab[g]];
        float i2  = iou * iou;
        float al  = s * (i2 * i2 * i2);
        align_anchor[idx] = al;
        atomicMax(max_metric + b * NGT + g, __float_as_uint(al));
        atomicMax(max_iou    + b * NGT + g, __float_as_uint(iou));
        label = glab[g];
        bb    = gbox[g];
    } else {
        label = CC;          // 80 = NUM_CLASSES
        bb    = gbox[0];     // argmax of all-zero mask -> gt 0
    }
    out_labels[idx] = (float)label;
    out_bboxes[idx] = bb;
}

// ---------------- Kernel E: scores (full coalesced tile write) -------------
__global__ __launch_bounds__(256) void score_kernel(
    const int*    __restrict__ gt_labels,
    const int*    __restrict__ assigned_gt,
    const float*  __restrict__ align_anchor,
    const unsigned* __restrict__ max_metric,
    const unsigned* __restrict__ max_iou,
    float*  __restrict__ out_scores)
{
    int t = blockIdx.x * 256 + threadIdx.x;   // global anchor index (exact)
    __shared__ int   s_lab[256];
    __shared__ float s_f[256];

    int b = t / LL;
    int g = assigned_gt[t];
    int label = CC;
    float f = 0.0f;
    if (g >= 0) {
        label = gt_labels[b * NGT + g];
        float mm = __uint_as_float(max_metric[b * NGT + g]);
        float mi = __uint_as_float(max_iou[b * NGT + g]);
        f = align_anchor[t] / (mm + FEPS) * mi;
    }
    s_lab[threadIdx.x] = label;
    s_f[threadIdx.x]   = f;
    __syncthreads();

    // 256 anchors * 80 classes = 5120 float4, contiguous & coalesced.
    vfloat4* outs = (vfloat4*)(out_scores + (size_t)blockIdx.x * 256 * CC);
    for (int i = threadIdx.x; i < 256 * CC / 4; i += 256) {
        int anchor = i / (CC / 4);
        int c4     = i % (CC / 4);
        int lab    = s_lab[anchor];
        vfloat4 v = {0.f, 0.f, 0.f, 0.f};
        int rel = lab - c4 * 4;
        if (rel >= 0 && rel < 4) v[rel] = s_f[anchor];
        __builtin_nontemporal_store(v, outs + i);
    }
}

extern "C" void kernel_launch(void* const* d_in, const int* in_sizes, int n_in,
                              void* d_out, int out_size, void* d_ws, size_t ws_size,
                              hipStream_t stream)
{
    const float*  pred_scores = (const float*)d_in[0];
    const float4* pred_bboxes = (const float4*)d_in[1];
    const float2* anchors     = (const float2*)d_in[2];
    const int*    gt_labels   = (const int*)d_in[3];
    const float4* gt_bboxes   = (const float4*)d_in[4];
    // d_in[5] = pad_gt_mask (all ones by construction)

    char* w = (char*)d_ws;
    // zeroed region (one memset): claim_count, claimant, max_metric, max_iou
    int*      claim_count  = (int*)(w);                 // B*L      = 537600 B
    int*      claimant     = (int*)(w + 537600);        // B*L      = 537600 B
    unsigned* max_metric   = (unsigned*)(w + 1075200);  // B*NGT    =   8192 B
    unsigned* max_iou      = (unsigned*)(w + 1083392);  // B*NGT    =   8192 B
    // non-zeroed (fully overwritten before read):
    int*      assigned_gt  = (int*)(w + 1091584);       // B*L      = 537600 B
    float*    align_anchor = (float*)(w + 1629184);     // B*L      = 537600 B

    float*  out        = (float*)d_out;
    float*  out_labels = out;                                   // B*L
    float4* out_bboxes = (float4*)(out + (size_t)BB * LL);      // B*L*4
    float*  out_scores = out + (size_t)BB * LL * 5;             // B*L*80

    (void)hipMemsetAsync(w, 0, 1091584, stream);

    topk_kernel<<<BB * NGT, 256, 0, stream>>>(
        pred_scores, pred_bboxes, anchors, gt_labels, gt_bboxes,
        claim_count, claimant);

    dim3 gridC((LL + 255) / 256, BB);
    resolve_kernel<<<gridC, 256, 0, stream>>>(
        pred_scores, pred_bboxes, gt_labels, gt_bboxes,
        claim_count, claimant, assigned_gt, align_anchor, max_metric, max_iou,
        out_labels, out_bboxes);

    score_kernel<<<(BB * LL) / 256, 256, 0, stream>>>(
        gt_labels, assigned_gt, align_anchor, max_metric, max_iou, out_scores);
}

// Round 8
// 92.961 us; speedup vs baseline: 1.0590x; 1.0590x over previous
//
#include <hip/hip_runtime.h>
#include <stdint.h>

#define BB   16
#define NGT  128
#define LL   8400
#define CC   80
#define KTOP 13
#define FEPS 1e-9f

typedef float vfloat4 __attribute__((ext_vector_type(4)));

__device__ __forceinline__ float iou_f(float4 g, float4 p) {
    float ix0 = fmaxf(g.x, p.x);
    float iy0 = fmaxf(g.y, p.y);
    float ix1 = fminf(g.z, p.z);
    float iy1 = fminf(g.w, p.w);
    float ow = fmaxf(ix1 - ix0, 0.0f);
    float oh = fmaxf(iy1 - iy0, 0.0f);
    float ov = ow * oh;
    float a1 = fmaxf(g.z - g.x, 0.0f) * fmaxf(g.w - g.y, 0.0f);
    float a2 = fmaxf(p.z - p.x, 0.0f) * fmaxf(p.w - p.y, 0.0f);
    return ov / (a1 + a2 - ov + FEPS);
}

// --------- Kernel A: exact top-13 per (b,gt) row + fused claim -------------
// ONE WAVE per row. Phase 1 scans anchors as float4 (2 anchors/load) in
// explicit batches of 8 independent loads -> registers (forced MLP), tests
// into two register bitmasks (bit t of mA/mB = anchors 2*(lane+64t)+{0,1}).
// Phase 2 walks own bits: bbox gather (L2) + iou; score gather only if
// iou>0 (iou==0 -> metric exactly 0.0 in reference). Merge: 13 rounds of
// wave argmax + owner-pop, winners parked in lanes 0..12, parallel claims.
// Key = (metric_bits << 32) | ~j -> max-order == (value desc, index asc),
// exactly jax.lax.top_k tie semantics. Zero-fill slots (<13 positive rows)
// provably have j < 26; lanes 0..12 inject virtual zero keys for their
// j=2L,2L+1 when outside the box (in-box ones arise naturally in the scan).
__global__ __launch_bounds__(64) void topk_kernel(
    const float*  __restrict__ pred_scores,   // B,L,C
    const float4* __restrict__ pred_bboxes,   // B,L
    const float2* __restrict__ anchors,       // L
    const int*    __restrict__ gt_labels,     // B,n
    const float4* __restrict__ gt_bboxes,     // B,n
    int* __restrict__ claim_count,            // B,L (zeroed)
    int* __restrict__ claimant)               // B,L (zeroed)
{
    int lane = threadIdx.x;
    int row  = blockIdx.x;                    // b*NGT + i
    int b    = row >> 7;
    int i_gt = row & (NGT - 1);

    float4 g  = gt_bboxes[row];
    int label = gt_labels[row];
    const float*   sc = pred_scores + (size_t)b * LL * CC + label;
    const float4*  pb = pred_bboxes + (size_t)b * LL;
    const vfloat4* a4 = (const vfloat4*)anchors;   // 4200 entries, 2 anchors each

    unsigned long long keys[KTOP];
#pragma unroll
    for (int k = 0; k < KTOP; ++k) keys[k] = 0ull;

    auto insert = [&](unsigned long long key) {
        if (key > keys[KTOP - 1]) {
            keys[KTOP - 1] = key;
#pragma unroll
            for (int k = KTOP - 1; k > 0; --k) {
                unsigned long long a = keys[k - 1], c2 = keys[k];
                keys[k - 1] = (c2 > a) ? c2 : a;
                keys[k]     = (c2 > a) ? a : c2;
            }
        }
    };
    auto eval_insert = [&](int j) {
        float4 pbx = pb[j];                      // L2-resident gather
        float iou = iou_f(g, pbx);
        unsigned long long key = (unsigned)(~(unsigned)j);
        if (iou > 0.0f) {                        // ~10%: score gather
            float s  = sc[(size_t)j * CC];
            float i2 = iou * iou;
            key |= ((unsigned long long)__float_as_uint(s * (i2 * i2 * i2)) << 32);
        }
        insert(key);
    };

    // ---- Phase 1: batched float4 scan -> register bitmasks (forced MLP) ----
    unsigned long long mA = 0ull, mB = 0ull;
    for (int b8 = 0; b8 < 8; ++b8) {
        vfloat4 v[8];
#pragma unroll
        for (int u = 0; u < 8; ++u)
            v[u] = a4[lane + ((b8 * 8 + u) << 6)];   // 8 independent loads
#pragma unroll
        for (int u = 0; u < 8; ++u) {
            int t = b8 * 8 + u;
            float dA = fminf(fminf(v[u].x - g.x, v[u].y - g.y),
                             fminf(g.z - v[u].x, g.w - v[u].y));
            float dB = fminf(fminf(v[u].z - g.x, v[u].w - g.y),
                             fminf(g.z - v[u].z, g.w - v[u].w));
            mA |= ((unsigned long long)(dA > FEPS)) << t;
            mB |= ((unsigned long long)(dB > FEPS)) << t;
        }
    }
    // tail: t=64 (f=4096+lane), t=65 (f=4160+lane, lane<40) -> eval inline
    {
        vfloat4 v0 = a4[4096 + lane];
        float dA = fminf(fminf(v0.x - g.x, v0.y - g.y),
                         fminf(g.z - v0.x, g.w - v0.y));
        float dB = fminf(fminf(v0.z - g.x, v0.w - g.y),
                         fminf(g.z - v0.z, g.w - v0.w));
        int f = 4096 + lane;
        if (dA > FEPS) eval_insert(2 * f);
        if (dB > FEPS) eval_insert(2 * f + 1);
        if (lane < 40) {
            vfloat4 v1 = a4[4160 + lane];
            float eA = fminf(fminf(v1.x - g.x, v1.y - g.y),
                             fminf(g.z - v1.x, g.w - v1.y));
            float eB = fminf(fminf(v1.z - g.x, v1.w - g.y),
                             fminf(g.z - v1.z, g.w - v1.w));
            int f1 = 4160 + lane;
            if (eA > FEPS) eval_insert(2 * f1);
            if (eB > FEPS) eval_insert(2 * f1 + 1);
        }
    }

    // virtual zero keys: lanes 0..12 own j = 2*lane, 2*lane+1 (t=0 bits)
    if (lane < KTOP) {
        if (!(mA & 1ull)) insert((unsigned long long)(unsigned)(~(unsigned)(2 * lane)));
        if (!(mB & 1ull)) insert((unsigned long long)(unsigned)(~(unsigned)(2 * lane + 1)));
    }

    // ---- Phase 2: walk own candidate bits ----
    while (mA) {
        int t = __ffsll(mA) - 1; mA &= mA - 1ull;
        eval_insert(2 * (lane + (t << 6)));
    }
    while (mB) {
        int t = __ffsll(mB) - 1; mB &= mB - 1ull;
        eval_insert(2 * (lane + (t << 6)) + 1);
    }

    // ---- Merge: 13 rounds wave-argmax + owner-pop; winners -> lanes 0..12 ----
    unsigned long long winner = 0ull;
    for (int r = 0; r < KTOP; ++r) {
        unsigned long long head = keys[0];
        unsigned long long m = head;
#pragma unroll
        for (int off = 1; off < 64; off <<= 1) {
            unsigned long long o = __shfl_xor(m, off, 64);
            if (o > m) m = o;
        }
        if (head == m && m != 0ull) {   // unique owner (keys distinct)
#pragma unroll
            for (int k = 0; k < KTOP - 1; ++k) keys[k] = keys[k + 1];
            keys[KTOP - 1] = 0ull;
        }
        if (lane == r) winner = m;
    }

    // ---- Parallel claims: recheck in-box, scatter atomics ----
    if (lane < KTOP && winner != 0ull) {
        int j = (int)(~(unsigned)(winner & 0xFFFFFFFFull));
        float2 ap = anchors[j];
        float d = fminf(fminf(ap.x - g.x, ap.y - g.y),
                        fminf(g.z - ap.x, g.w - ap.y));
        if (d > FEPS) {
            atomicAdd(claim_count + b * LL + j, 1);
            atomicMax(claimant + b * LL + j, i_gt);
        }
    }
}

// ------- Kernel C: resolve contested + per-GT maxes + labels/bboxes --------
__global__ __launch_bounds__(256) void resolve_kernel(
    const float*  __restrict__ pred_scores,
    const float4* __restrict__ pred_bboxes,
    const int*    __restrict__ gt_labels,
    const float4* __restrict__ gt_bboxes,
    const int*    __restrict__ claim_count,
    const int*    __restrict__ claimant,
    int*      __restrict__ assigned_gt,
    float*    __restrict__ align_anchor,
    unsigned* __restrict__ max_metric,
    unsigned* __restrict__ max_iou,
    float*    __restrict__ out_labels,
    float4*   __restrict__ out_bboxes)
{
    int b = blockIdx.y;
    int j = blockIdx.x * 256 + threadIdx.x;

    __shared__ float4 gbox[NGT];
    __shared__ int    glab[NGT];
    if (threadIdx.x < NGT) {
        gbox[threadIdx.x] = gt_bboxes[b * NGT + threadIdx.x];
        glab[threadIdx.x] = gt_labels[b * NGT + threadIdx.x];
    }
    __syncthreads();
    if (j >= LL) return;

    int idx = b * LL + j;
    int cnt = claim_count[idx];
    int g = -1;
    float4 p = pred_bboxes[(size_t)b * LL + j];

    if (cnt == 1) {
        g = claimant[idx];
    } else if (cnt > 1) {
        // argmax_i iou over ALL gts, first-max tie-break (strict >)
        float best = -1.0f;
        int   bi   = 0;
        for (int i = 0; i < NGT; ++i) {
            float iou = iou_f(gbox[i], p);
            if (iou > best) { best = iou; bi = i; }
        }
        g = bi;
    }
    assigned_gt[idx] = g;

    int label; float4 bb;
    if (g >= 0) {
        float iou = iou_f(gbox[g], p);
        float s   = pred_scores[((size_t)b * LL + j) * CC + glab[g]];
        float i2  = iou * iou;
        float al  = s * (i2 * i2 * i2);
        align_anchor[idx] = al;
        atomicMax(max_metric + b * NGT + g, __float_as_uint(al));
        atomicMax(max_iou    + b * NGT + g, __float_as_uint(iou));
        label = glab[g];
        bb    = gbox[g];
    } else {
        label = CC;          // 80 = NUM_CLASSES
        bb    = gbox[0];     // argmax of all-zero mask -> gt 0
    }
    out_labels[idx] = (float)label;
    out_bboxes[idx] = bb;
}

// ---------------- Kernel E: scores (full coalesced tile write) -------------
__global__ __launch_bounds__(256) void score_kernel(
    const int*    __restrict__ gt_labels,
    const int*    __restrict__ assigned_gt,
    const float*  __restrict__ align_anchor,
    const unsigned* __restrict__ max_metric,
    const unsigned* __restrict__ max_iou,
    float*  __restrict__ out_scores)
{
    int t = blockIdx.x * 256 + threadIdx.x;   // global anchor index (exact)
    __shared__ int   s_lab[256];
    __shared__ float s_f[256];

    int b = t / LL;
    int g = assigned_gt[t];
    int label = CC;
    float f = 0.0f;
    if (g >= 0) {
        label = gt_labels[b * NGT + g];
        float mm = __uint_as_float(max_metric[b * NGT + g]);
        float mi = __uint_as_float(max_iou[b * NGT + g]);
        f = align_anchor[t] / (mm + FEPS) * mi;
    }
    s_lab[threadIdx.x] = label;
    s_f[threadIdx.x]   = f;
    __syncthreads();

    // 256 anchors * 80 classes = 5120 float4, contiguous & coalesced.
    vfloat4* outs = (vfloat4*)(out_scores + (size_t)blockIdx.x * 256 * CC);
    for (int i = threadIdx.x; i < 256 * CC / 4; i += 256) {
        int anchor = i / (CC / 4);
        int c4     = i % (CC / 4);
        int lab    = s_lab[anchor];
        vfloat4 v = {0.f, 0.f, 0.f, 0.f};
        int rel = lab - c4 * 4;
        if (rel >= 0 && rel < 4) v[rel] = s_f[anchor];
        __builtin_nontemporal_store(v, outs + i);
    }
}

extern "C" void kernel_launch(void* const* d_in, const int* in_sizes, int n_in,
                              void* d_out, int out_size, void* d_ws, size_t ws_size,
                              hipStream_t stream)
{
    const float*  pred_scores = (const float*)d_in[0];
    const float4* pred_bboxes = (const float4*)d_in[1];
    const float2* anchors     = (const float2*)d_in[2];
    const int*    gt_labels   = (const int*)d_in[3];
    const float4* gt_bboxes   = (const float4*)d_in[4];
    // d_in[5] = pad_gt_mask (all ones by construction)

    char* w = (char*)d_ws;
    // zeroed region (one memset): claim_count, claimant, max_metric, max_iou
    int*      claim_count  = (int*)(w);                 // B*L      = 537600 B
    int*      claimant     = (int*)(w + 537600);        // B*L      = 537600 B
    unsigned* max_metric   = (unsigned*)(w + 1075200);  // B*NGT    =   8192 B
    unsigned* max_iou      = (unsigned*)(w + 1083392);  // B*NGT    =   8192 B
    // non-zeroed (fully overwritten before read):
    int*      assigned_gt  = (int*)(w + 1091584);       // B*L      = 537600 B
    float*    align_anchor = (float*)(w + 1629184);     // B*L      = 537600 B

    float*  out        = (float*)d_out;
    float*  out_labels = out;                                   // B*L
    float4* out_bboxes = (float4*)(out + (size_t)BB * LL);      // B*L*4
    float*  out_scores = out + (size_t)BB * LL * 5;             // B*L*80

    (void)hipMemsetAsync(w, 0, 1091584, stream);

    topk_kernel<<<BB * NGT, 64, 0, stream>>>(
        pred_scores, pred_bboxes, anchors, gt_labels, gt_bboxes,
        claim_count, claimant);

    dim3 gridC((LL + 255) / 256, BB);
    resolve_kernel<<<gridC, 256, 0, stream>>>(
        pred_scores, pred_bboxes, gt_labels, gt_bboxes,
        claim_count, claimant, assigned_gt, align_anchor, max_metric, max_iou,
        out_labels, out_bboxes);

    score_kernel<<<(BB * LL) / 256, 256, 0, stream>>>(
        gt_labels, assigned_gt, align_anchor, max_metric, max_iou, out_scores);
}